// Round 8
// baseline (139.228 us; speedup 1.0000x reference)
//
#include <hip/hip_runtime.h>

// FastAttention (Performer linear attention), B=4 H=8 N=4096 D=F=64, fp32.
// Champion structure (prep + pass1 + pass2), R8 micro-tune:
//   prep : zero per-head accumulators; build proj*log2(e) bf16 fragment table
//   pass1: ALL K/V raw loads issued first (16 dwordx4/lane in flight, NT),
//          then convert+MFMA: k' = exp2(k @ proj'); atomicAdd partials -> ws
//   pass2: Q raw loads (NT) issued FIRST, then L2-hot table/stats; 6 blk/CU;
//          out = q'*ctx/(q'.(ksum+1e-6))
// Column permutation: MFMA tile ft computes feature f = fp*4+ft (fp=lane&15),
// so V loads, stats and out stores are all dwordx4.
// ws: [0..4096) floats = 32 heads x (ksum[64]||ctx[64]); then 4096-short table
//     table index: (ft*2+half)*512 + lane*8 + j ; value bf16(proj[f][d]*log2e)

#define NHEADS 32
#define SEQ    4096
#define DDIM   64
#define ACC_FLOATS (NHEADS * 128)
#define LOG2E 1.44269504088896341f

typedef __attribute__((ext_vector_type(8))) short short8;
typedef __attribute__((ext_vector_type(4))) float floatx4;

__device__ __forceinline__ short f2bf(float x) {
    unsigned int u = __float_as_uint(x);
    u += 0x7fffu + ((u >> 16) & 1u);
    return (short)(u >> 16);
}

__device__ __forceinline__ short8 cvt8(floatx4 a, floatx4 b) {
    short8 t;
    t[0] = f2bf(a[0]); t[1] = f2bf(a[1]); t[2] = f2bf(a[2]); t[3] = f2bf(a[3]);
    t[4] = f2bf(b[0]); t[5] = f2bf(b[1]); t[6] = f2bf(b[2]); t[7] = f2bf(b[3]);
    return t;
}

__device__ __forceinline__ floatx4 ldnt4(const float* __restrict__ p) {
    return __builtin_nontemporal_load((const floatx4*)p);
}

__device__ __forceinline__ void load_bfrag_ws(const short* __restrict__ pbf,
                                              int lane, short8 bfrag[4][2]) {
#pragma unroll
    for (int ft = 0; ft < 4; ++ft)
#pragma unroll
        for (int half = 0; half < 2; ++half)
            bfrag[ft][half] = *(const short8*)(pbf + (ft * 2 + half) * 512 + lane * 8);
}

// blocks 0..3: zero accumulators (256 thr x 4 elems). block 4: build table.
__global__ __launch_bounds__(256) void fa_prep(const float* __restrict__ proj,
                                               float* __restrict__ ws) {
    const int tid = threadIdx.x;
    if (blockIdx.x < 4) {
        floatx4 z = {0.f, 0.f, 0.f, 0.f};
        *(floatx4*)(ws + (blockIdx.x * 256 + tid) * 4) = z;
        return;
    }
    short* pbf = (short*)(ws + ACC_FLOATS);
#pragma unroll
    for (int i = 0; i < 16; ++i) {
        int idx  = tid * 16 + i;          // 0..4095
        int ft2h = idx >> 9;              // (ft*2+half)
        int rem  = idx & 511;
        int lane = rem >> 3;
        int j    = rem & 7;
        int ft   = ft2h >> 1;
        int half = ft2h & 1;
        int fp   = lane & 15;
        int g    = lane >> 4;
        pbf[idx] = f2bf(proj[(fp * 4 + ft) * DDIM + half * 32 + g * 8 + j] * LOG2E);
    }
}

__global__ __launch_bounds__(256, 4) void fa_pass1(const float* __restrict__ K,
                                                   const float* __restrict__ V,
                                                   float* __restrict__ ws) {
    const int head = blockIdx.x >> 5;   // 32 heads x 32 segments of 128 rows
    const int seg  = blockIdx.x & 31;
    const int tid  = threadIdx.x;
    const int w    = tid >> 6;
    const int lane = tid & 63;
    const int fp   = lane & 15;
    const int g    = lane >> 4;
    const long hbase = (long)head * SEQ;
    const int rowb = seg * 128 + w * 16;

    // ---- issue ALL raw global loads first (16 dwordx4 per lane in flight)
    floatx4 kraw[2][4];
#pragma unroll
    for (int it = 0; it < 2; ++it) {
        const float* ap = K + (hbase + rowb + it * 64 + fp) * DDIM;
        kraw[it][0] = ldnt4(ap + g * 8);
        kraw[it][1] = ldnt4(ap + g * 8 + 4);
        kraw[it][2] = ldnt4(ap + 32 + g * 8);
        kraw[it][3] = ldnt4(ap + 32 + g * 8 + 4);
    }
    floatx4 vraw[2][4];
#pragma unroll
    for (int it = 0; it < 2; ++it)
#pragma unroll
        for (int r = 0; r < 4; ++r)
            vraw[it][r] =
                ldnt4(V + (hbase + rowb + it * 64 + g * 4 + r) * DDIM + fp * 4);

    // L2-hot fragment table (independent of the above)
    const short* pbf = (const short*)(ws + ACC_FLOATS);
    short8 bfrag[4][2];
    load_bfrag_ws(pbf, lane, bfrag);

    float ksum[4] = {0.f, 0.f, 0.f, 0.f};
    float ctx[4]  = {0.f, 0.f, 0.f, 0.f};

#pragma unroll
    for (int it = 0; it < 2; ++it) {
        short8 a0 = cvt8(kraw[it][0], kraw[it][1]);
        short8 a1 = cvt8(kraw[it][2], kraw[it][3]);

        floatx4 acc[4];
#pragma unroll
        for (int ft = 0; ft < 4; ++ft) {
            floatx4 z = {0.f, 0.f, 0.f, 0.f};
            z = __builtin_amdgcn_mfma_f32_16x16x32_bf16(a0, bfrag[ft][0], z, 0, 0, 0);
            z = __builtin_amdgcn_mfma_f32_16x16x32_bf16(a1, bfrag[ft][1], z, 0, 0, 0);
            acc[ft] = z;
        }
        // C layout: col f = fp*4+ft, row = rowb + it*64 + g*4 + r
#pragma unroll
        for (int r = 0; r < 4; ++r) {
#pragma unroll
            for (int ft = 0; ft < 4; ++ft) {
                float kp = __builtin_amdgcn_exp2f(acc[ft][r]);
                ksum[ft] += kp;
                ctx[ft]  += kp * vraw[it][r][ft];
            }
        }
    }

#pragma unroll
    for (int ft = 0; ft < 4; ++ft) {
        ksum[ft] += __shfl_xor(ksum[ft], 16); ksum[ft] += __shfl_xor(ksum[ft], 32);
        ctx[ft]  += __shfl_xor(ctx[ft], 16);  ctx[ft]  += __shfl_xor(ctx[ft], 32);
    }

    __shared__ float red[4][128];
    if (lane < 16) {
#pragma unroll
        for (int ft = 0; ft < 4; ++ft) {
            red[w][fp * 4 + ft]      = ksum[ft];
            red[w][64 + fp * 4 + ft] = ctx[ft];
        }
    }
    __syncthreads();
    if (tid < 128) {
        float s = red[0][tid] + red[1][tid] + red[2][tid] + red[3][tid];
        atomicAdd(ws + head * 128 + tid, s);
    }
}

__global__ __launch_bounds__(256, 6) void fa_pass2(const float* __restrict__ Q,
                                                   const float* __restrict__ ws,
                                                   float* __restrict__ out) {
    const int head = blockIdx.x >> 6;   // 32 heads x 64 segments of 64 rows
    const int seg  = blockIdx.x & 63;
    const int tid  = threadIdx.x;
    const int w    = tid >> 6;
    const int lane = tid & 63;
    const int fp   = lane & 15;
    const int g    = lane >> 4;
    const long hbase = (long)head * SEQ;
    const int row0 = seg * 64 + w * 16;

    // ---- issue the HBM Q loads FIRST (only long-latency loads here)
    const float* ap = Q + (hbase + row0 + fp) * DDIM;
    floatx4 qraw[4];
    qraw[0] = ldnt4(ap + g * 8);
    qraw[1] = ldnt4(ap + g * 8 + 4);
    qraw[2] = ldnt4(ap + 32 + g * 8);
    qraw[3] = ldnt4(ap + 32 + g * 8 + 4);

    // L2-hot: fragment table + per-head stats
    const short* pbf = (const short*)(ws + ACC_FLOATS);
    short8 bfrag[4][2];
    load_bfrag_ws(pbf, lane, bfrag);

    floatx4 ksr  = *(const floatx4*)(ws + head * 128 + fp * 4);
    floatx4 ctxr = *(const floatx4*)(ws + head * 128 + 64 + fp * 4);
#pragma unroll
    for (int ft = 0; ft < 4; ++ft) ksr[ft] += 1e-6f;

    short8 afrag0 = cvt8(qraw[0], qraw[1]);
    short8 afrag1 = cvt8(qraw[2], qraw[3]);

    float qp[4][4];
    float denom[4] = {0.f, 0.f, 0.f, 0.f};
#pragma unroll
    for (int ft = 0; ft < 4; ++ft) {
        floatx4 z = {0.f, 0.f, 0.f, 0.f};
        z = __builtin_amdgcn_mfma_f32_16x16x32_bf16(afrag0, bfrag[ft][0], z, 0, 0, 0);
        z = __builtin_amdgcn_mfma_f32_16x16x32_bf16(afrag1, bfrag[ft][1], z, 0, 0, 0);
#pragma unroll
        for (int r = 0; r < 4; ++r) {
            float e = __builtin_amdgcn_exp2f(z[r]);
            qp[ft][r] = e;
            denom[r] += e * ksr[ft];
        }
    }

#pragma unroll
    for (int r = 0; r < 4; ++r) {
        denom[r] += __shfl_xor(denom[r], 1);
        denom[r] += __shfl_xor(denom[r], 2);
        denom[r] += __shfl_xor(denom[r], 4);
        denom[r] += __shfl_xor(denom[r], 8);
        denom[r] = 1.0f / denom[r];
    }

#pragma unroll
    for (int r = 0; r < 4; ++r) {
        floatx4 o;
#pragma unroll
        for (int ft = 0; ft < 4; ++ft)
            o[ft] = qp[ft][r] * ctxr[ft] * denom[r];
        *(floatx4*)(out + (hbase + row0 + g * 4 + r) * DDIM + fp * 4) = o;
    }
}

extern "C" void kernel_launch(void* const* d_in, const int* in_sizes, int n_in,
                              void* d_out, int out_size, void* d_ws, size_t ws_size,
                              hipStream_t stream) {
    const float* q    = (const float*)d_in[0];
    const float* k    = (const float*)d_in[1];
    const float* v    = (const float*)d_in[2];
    const float* proj = (const float*)d_in[3];
    float* out = (float*)d_out;
    float* ws  = (float*)d_ws;

    fa_prep<<<5, 256, 0, stream>>>(proj, ws);
    fa_pass1<<<NHEADS * 32, 256, 0, stream>>>(k, v, ws);
    fa_pass2<<<NHEADS * 64, 256, 0, stream>>>(q, ws, out);
}